// Round 4
// baseline (254.203 us; speedup 1.0000x reference)
//
#include <hip/hip_runtime.h>
#include <math.h>

// ClownSelector R4: R3 design with the illegal asm fences removed.
//
// lane = expert (E=64 = wave width). Block = 32 tokens, 4 waves.
// Wave w computes 9 dot rows: its 8 tokens + 1 extra (w0: s0-2 halo,
// w1: s0-1 halo, w2/w3: duplicate row into junk LDS slots).
// Per 64-d chunk:
//   - proto chunk staged global->LDS once per BLOCK, each lane reads its
//     expert's 16 float4s -> 64 VGPRs
//   - x row chunk streamed via 4x s_load_dwordx16 into SGPRs (wave-uniform),
//     inner loop is pure v_fmac_f32 vacc, s_x, v_p (1 SGPR src per VALU: ok)
//   - every stream wait is a FULL lgkmcnt(0) drain, so out-of-order SMEM
//     returns and any foreign lgkm ops (shfl/ds_read) are safely covered;
//     no partial-count or selective fences needed for correctness
// Epilogue: dots (scaled by 1/||x||) -> LDS, window-3 sum, top-2 butterfly,
// w1 = 1/(1+exp((l2-l1)/3)) (softmax denominator cancels).

#define BB 8
#define SS 2048
#define DD 1024
#define EE 64
#define TKB 32         // tokens per block
#define RPW 8          // tokens per wave
#define NRW 9          // dot rows per wave (8 + halo/dup)
#define NCH 16         // 64-d chunks
#define EPSV 1e-8f

typedef int v16i __attribute__((ext_vector_type(16)));

// issue one 64B scalar load (16 floats -> 16 SGPRs)
#define SL(dst, a, off) \
  asm volatile("s_load_dwordx16 %0, %1, " off : "=s"(dst) : "s"(a))

// 4 fmacs pairing x floats k0..k0+3 of vector Vv with proto quad q
#define FM4(i, Vv, k0, q)                              \
  acc[i] += __int_as_float(Vv[k0 + 0]) * p4[q].x;      \
  acc[i] += __int_as_float(Vv[k0 + 1]) * p4[q].y;      \
  acc[i] += __int_as_float(Vv[k0 + 2]) * p4[q].z;      \
  acc[i] += __int_as_float(Vv[k0 + 3]) * p4[q].w;

#define FM16(i, Vv, q0) \
  FM4(i, Vv, 0, q0) FM4(i, Vv, 4, (q0) + 1) FM4(i, Vv, 8, (q0) + 2) FM4(i, Vv, 12, (q0) + 3)

// ---- Kernel A: repack proto[e][d] -> ptt[d/4][e] (float4) ------------------
__global__ __launch_bounds__(256) void repack_proto(
    const float* __restrict__ proto, float4* __restrict__ ptt) {
  const int gid = blockIdx.x * 256 + threadIdx.x;  // 0..16383
  const int dd = gid >> 6;
  const int e  = gid & 63;
  ptt[gid] = *(const float4*)(proto + (size_t)e * DD + dd * 4);
}

// ---- Kernel B: fused norms + dots + window + top2 --------------------------
__global__ __launch_bounds__(256) void router_fused(
    const float* __restrict__ x, const float4* __restrict__ ptt,
    float* __restrict__ out) {
  __shared__ float4 pst[NCH][EE];   // proto chunk: pst[g][e] = d 4g..4g+3 (16 KB)
  __shared__ float  dls[36][EE];    // dot rows 0..33 real, 34/35 junk (9 KB)

  const int lane = threadIdx.x & 63;
  const int w    = __builtin_amdgcn_readfirstlane(threadIdx.x >> 6);
  const int bid  = blockIdx.x;
  const int b    = bid >> 6;          // 64 blocks per batch
  const int s0   = (bid & 63) * TKB;

  // row assignment (wave-uniform)
  int rs[NRW];
  int lr0;
  if (w == 0)      { rs[0] = (s0 >= 2) ? s0 - 2 : 0; lr0 = 0; }
  else if (w == 1) { rs[0] = (s0 >= 1) ? s0 - 1 : 0; lr0 = 1; }
  else             { rs[0] = s0 + 8 * w;             lr0 = 32 + w; }  // junk slot
#pragma unroll
  for (int i = 1; i < NRW; ++i) rs[i] = s0 + 8 * w + (i - 1);

  const float* xb = x + (size_t)b * SS * DD;

  // ---- norm pre-pass: 1/max(||x_row||, eps), coalesced + butterfly ----
  float inv[NRW];
#pragma unroll
  for (int i = 0; i < NRW; ++i) {
    const float4* xr4 = (const float4*)(xb + (size_t)rs[i] * DD);
    float ssum = 0.0f;
#pragma unroll
    for (int j = 0; j < 4; ++j) {
      const float4 v = xr4[j * 64 + lane];
      ssum += v.x * v.x + v.y * v.y + v.z * v.z + v.w * v.w;
    }
#pragma unroll
    for (int m = 1; m < 64; m <<= 1) ssum += __shfl_xor(ssum, m);
    inv[i] = 1.0f / fmaxf(sqrtf(ssum), EPSV);
  }

  float acc[NRW];
#pragma unroll
  for (int i = 0; i < NRW; ++i) acc[i] = 0.0f;

  const unsigned long long xbu = (unsigned long long)(uintptr_t)xb;

  for (int c = 0; c < NCH; ++c) {
    __syncthreads();  // prior chunk's pst reads complete before overwrite
    // stage proto chunk: 4 float4 per wave, coalesced 1 KB loads
#pragma unroll
    for (int q = 0; q < 4; ++q) {
      const int g = w * 4 + q;
      pst[g][lane] = ptt[((size_t)c * 16 + g) * 64 + lane];
    }
    __syncthreads();

    // this lane's expert fragment: 64 d-values in 16 float4s (64 VGPRs).
    // Compiler inserts the lgkm wait before first use; our in-stream full
    // drains cover any still-in-flight ds_reads as well.
    float4 p4[16];
#pragma unroll
    for (int g = 0; g < 16; ++g) p4[g] = pst[g][lane];

#pragma unroll
    for (int i = 0; i < NRW; ++i) {
      const unsigned long long xa =
          xbu + (unsigned long long)rs[i] * (DD * 4ull) + (unsigned)(c * 256);
      v16i A, B, C, D;
      SL(A, xa, "0x0");
      SL(B, xa, "0x40");
      SL(C, xa, "0x80");
      SL(D, xa, "0xc0");
      // SMEM may return out-of-order: full drain is the only safe wait
      asm volatile("s_waitcnt lgkmcnt(0)" : "+s"(A), "+s"(B), "+s"(C), "+s"(D));
      FM16(i, A, 0)
      FM16(i, B, 4)
      FM16(i, C, 8)
      FM16(i, D, 12)
    }
  }

  // ---- publish normalized dots ----
#pragma unroll
  for (int i = 0; i < NRW; ++i) {
    const int lri = (i == 0) ? lr0 : (8 * w + i + 1);
    dls[lri][lane] = acc[i] * inv[i];
  }
  __syncthreads();

  // ---- window-3 sum + top-2 butterfly + renorm softmax ----
#pragma unroll
  for (int k = 0; k < RPW; ++k) {
    const int tl = 8 * w + k;  // local token; logits rows tl, tl+1, tl+2
    float v1 = dls[tl][lane] + dls[tl + 1][lane] + dls[tl + 2][lane];
    int   i1 = lane;
    float v2 = -INFINITY;
    int   i2 = 0;
#pragma unroll
    for (int m = 1; m < 64; m <<= 1) {
      const float ov1 = __shfl_xor(v1, m);
      const int   oi1 = __shfl_xor(i1, m);
      const float ov2 = __shfl_xor(v2, m);
      const int   oi2 = __shfl_xor(i2, m);
      const bool o_beats = (ov1 > v1) || (ov1 == v1 && oi1 < i1);
      if (o_beats) {
        const bool v1_beats_o2 = (v1 > ov2) || (v1 == ov2 && i1 < oi2);
        v2 = v1_beats_o2 ? v1 : ov2;
        i2 = v1_beats_o2 ? i1 : oi2;
        v1 = ov1;
        i1 = oi1;
      } else {
        const bool o1_beats_v2 = (ov1 > v2) || (ov1 == v2 && oi1 < i2);
        if (o1_beats_v2) { v2 = ov1; i2 = oi1; }
      }
    }
    if (lane == 0) {
      const float ex = expf((v2 - v1) * (1.0f / 3.0f));  // <= 1
      const float w1 = 1.0f / (1.0f + ex);
      const size_t t = ((size_t)b * SS + s0 + tl) * 2;
      *(float2*)(out + t) = make_float2((float)i1, (float)i2);
      *(float2*)(out + (size_t)BB * SS * 2 + t) = make_float2(w1, ex * w1);
    }
  }
}

extern "C" void kernel_launch(void* const* d_in, const int* in_sizes, int n_in,
                              void* d_out, int out_size, void* d_ws, size_t ws_size,
                              hipStream_t stream) {
  const float* x     = (const float*)d_in[0];
  const float* proto = (const float*)d_in[1];
  // d_in[2] = attn_mask: unused by the reference output path.
  float* out = (float*)d_out;
  float4* ptt = (float4*)d_ws;  // 256 KiB repacked prototypes

  repack_proto<<<dim3(64), dim3(256), 0, stream>>>(proto, ptt);
  router_fused<<<dim3(BB * (SS / TKB)), dim3(256), 0, stream>>>(x, ptt, out);
}

// Round 5
// 169.835 us; speedup vs baseline: 1.4968x; 1.4968x over previous
//
#include <hip/hip_runtime.h>
#include <math.h>

// ClownSelector R5: vector-pipe x staging + LDS-broadcast dots.
//
// lane = expert (E=64 = wave width). Block = 32 tokens, 4 waves, grid 512
// (2 blocks/CU -> cross-block overlap over barriers).
// Per 64-d chunk:
//   - x rows (34 = 32 + 2-row causal halo) staged global->LDS with coalesced
//     per-lane float4 loads (full HBM BW path); sum-of-squares for the L2
//     norm is fused into staging (each 16-thread group owns one row's 16
//     float4 slots) -> x is read from HBM exactly ONCE
//   - proto chunk staged global->LDS once per block; each lane keeps its
//     expert's 64 d-values in 16 float4 VGPRs
//   - dot loop: wave-uniform ds_read_b128 of x (HW broadcast, conflict-free)
//     against the VGPR proto fragment; two accumulators per row alternated
//     A,B,A,B so the fmac dep distance (4 cyc) matches issue (2x2 cyc)
// Norms: 16-lane shfl_xor group reduce, no atomics. Epilogue: window-3 sum,
// top-2 butterfly, w1 = 1/(1+exp((l2-l1)/3)) (softmax denominator cancels).

#define BB 8
#define SS 2048
#define DD 1024
#define EE 64
#define TKB 32          // output tokens per block
#define NRB 34          // dot rows per block (32 + 2 halo)
#define NCH 16          // 64-d chunks
#define EPSV 1e-8f

// ---- Kernel A: repack proto[e][d] -> ptt[d/4][e] (float4) ------------------
__global__ __launch_bounds__(256) void repack_proto(
    const float* __restrict__ proto, float4* __restrict__ ptt) {
  const int gid = blockIdx.x * 256 + threadIdx.x;  // 0..16383
  const int dd = gid >> 6;
  const int e  = gid & 63;
  ptt[gid] = *(const float4*)(proto + (size_t)e * DD + dd * 4);
}

// ---- Kernel B: fused norms + dots + window + top2 --------------------------
__global__ __launch_bounds__(256) void router_v5(
    const float* __restrict__ x, const float4* __restrict__ ptt,
    float* __restrict__ out) {
  __shared__ float  xs[NRB][64];    // x chunk, row-major         (8704 B)
  __shared__ float4 pst[NCH][EE];   // proto chunk pst[g][e]      (16384 B)
  __shared__ float  dls[NRB][EE];   // normalized dot rows        (8704 B)
  __shared__ float  nsq[NRB];       // per-row sum of squares

  const int t    = threadIdx.x;
  const int lane = t & 63;
  const int w    = __builtin_amdgcn_readfirstlane(t >> 6);
  const int b    = blockIdx.x >> 6;          // 64 blocks per batch
  const int s0   = (blockIdx.x & 63) * TKB;

  const float* xb = x + (size_t)b * SS * DD;

  // staging rows for this thread (chunk-invariant): slots = t, t+256, t+512
  const int f4  = t & 15;              // float4 slot within row
  const int r0  = t >> 4;              // rows 0..15
  const int r1  = r0 + 16;             // rows 16..31
  const int r2  = r0 + 32;             // rows 32..33 (threads t<32 only)
  int g0 = s0 - 2 + r0; if (g0 < 0) g0 = 0;   // clamp: halo replicates token 0
  const int g1 = s0 - 2 + r1;
  const int g2 = s0 - 2 + r2;
  const float* xr0 = xb + (size_t)g0 * DD + f4 * 4;
  const float* xr1 = xb + (size_t)g1 * DD + f4 * 4;
  const float* xr2 = xb + (size_t)g2 * DD + f4 * 4;

  // dot-row range for this wave: 9,9,8,8 rows
  const int wstart = (w < 2) ? 9 * w : 18 + 8 * (w - 2);
  const int wcnt   = (w < 2) ? 9 : 8;

  float q0 = 0.0f, q1 = 0.0f, q2 = 0.0f;  // fused norm partials
  float accA[9], accB[9];
#pragma unroll
  for (int i = 0; i < 9; ++i) { accA[i] = 0.0f; accB[i] = 0.0f; }

  for (int c = 0; c < NCH; ++c) {
    __syncthreads();  // previous chunk's xs/pst reads complete
    {  // ---- stage x (coalesced float4) + fused sumsq ----
      const float4 v0 = *(const float4*)(xr0 + c * 64);
      const float4 v1 = *(const float4*)(xr1 + c * 64);
      *(float4*)(&xs[r0][f4 * 4]) = v0;
      *(float4*)(&xs[r1][f4 * 4]) = v1;
      q0 += v0.x * v0.x + v0.y * v0.y + v0.z * v0.z + v0.w * v0.w;
      q1 += v1.x * v1.x + v1.y * v1.y + v1.z * v1.z + v1.w * v1.w;
      if (t < 32) {
        const float4 v2 = *(const float4*)(xr2 + c * 64);
        *(float4*)(&xs[r2][f4 * 4]) = v2;
        q2 += v2.x * v2.x + v2.y * v2.y + v2.z * v2.z + v2.w * v2.w;
      }
    }
    // ---- stage proto chunk: 4 float4 per thread, coalesced ----
#pragma unroll
    for (int q = 0; q < 4; ++q) {
      const int g = w + 4 * q;
      pst[g][lane] = ptt[((size_t)c * 16 + g) * 64 + lane];
    }
    __syncthreads();

    // this lane's expert fragment: 64 d-values in 16 float4 VGPRs
    float4 p4[16];
#pragma unroll
    for (int g = 0; g < 16; ++g) p4[g] = pst[g][lane];

    // ---- dots: wave-uniform broadcast reads of x vs VGPR proto ----
#pragma unroll
    for (int i = 0; i < 9; ++i) {
      if (i < wcnt) {
        const int lr = wstart + i;
#pragma unroll
        for (int v4 = 0; v4 < 16; ++v4) {
          const float4 xv = *(const float4*)(&xs[lr][v4 * 4]);
          accA[i] += xv.x * p4[v4].x;
          accB[i] += xv.y * p4[v4].y;
          accA[i] += xv.z * p4[v4].z;
          accB[i] += xv.w * p4[v4].w;
        }
      }
    }
  }

  // ---- norms: reduce sumsq within each 16-thread row group ----
#pragma unroll
  for (int m = 1; m < 16; m <<= 1) {
    q0 += __shfl_xor(q0, m);
    q1 += __shfl_xor(q1, m);
    q2 += __shfl_xor(q2, m);
  }
  if ((t & 15) == 0) {
    nsq[r0] = q0;
    nsq[r1] = q1;
    if (t < 32) nsq[r2] = q2;
  }
  __syncthreads();

  // ---- publish normalized dots ----
#pragma unroll
  for (int i = 0; i < 9; ++i) {
    if (i < wcnt) {
      const int lr = wstart + i;
      const float inv = 1.0f / fmaxf(sqrtf(nsq[lr]), EPSV);
      dls[lr][lane] = (accA[i] + accB[i]) * inv;
    }
  }
  __syncthreads();

  // ---- window-3 sum + top-2 butterfly + renorm softmax ----
#pragma unroll
  for (int k = 0; k < 8; ++k) {
    const int tl = 8 * w + k;  // local token; window rows tl, tl+1, tl+2
    float v1 = dls[tl][lane] + dls[tl + 1][lane] + dls[tl + 2][lane];
    int   i1 = lane;
    float v2 = -INFINITY;
    int   i2 = 0;
#pragma unroll
    for (int m = 1; m < 64; m <<= 1) {
      const float ov1 = __shfl_xor(v1, m);
      const int   oi1 = __shfl_xor(i1, m);
      const float ov2 = __shfl_xor(v2, m);
      const int   oi2 = __shfl_xor(i2, m);
      const bool o_beats = (ov1 > v1) || (ov1 == v1 && oi1 < i1);
      if (o_beats) {
        const bool v1_beats_o2 = (v1 > ov2) || (v1 == ov2 && i1 < oi2);
        v2 = v1_beats_o2 ? v1 : ov2;
        i2 = v1_beats_o2 ? i1 : oi2;
        v1 = ov1;
        i1 = oi1;
      } else {
        const bool o1_beats_v2 = (ov1 > v2) || (ov1 == v2 && oi1 < i2);
        if (o1_beats_v2) { v2 = ov1; i2 = oi1; }
      }
    }
    if (lane == 0) {
      const float ex = expf((v2 - v1) * (1.0f / 3.0f));  // <= 1
      const float w1 = 1.0f / (1.0f + ex);
      const size_t o = ((size_t)b * SS + s0 + tl) * 2;
      *(float2*)(out + o) = make_float2((float)i1, (float)i2);
      *(float2*)(out + (size_t)BB * SS * 2 + o) = make_float2(w1, ex * w1);
    }
  }
}

extern "C" void kernel_launch(void* const* d_in, const int* in_sizes, int n_in,
                              void* d_out, int out_size, void* d_ws, size_t ws_size,
                              hipStream_t stream) {
  const float* x     = (const float*)d_in[0];
  const float* proto = (const float*)d_in[1];
  // d_in[2] = attn_mask: unused by the reference output path.
  float* out = (float*)d_out;
  float4* ptt = (float4*)d_ws;  // 256 KiB repacked prototypes

  repack_proto<<<dim3(64), dim3(256), 0, stream>>>(proto, ptt);
  router_v5<<<dim3(BB * (SS / TKB)), dim3(256), 0, stream>>>(x, ptt, out);
}

// Round 6
// 153.765 us; speedup vs baseline: 1.6532x; 1.1045x over previous
//
#include <hip/hip_runtime.h>
#include <math.h>

// ClownSelector R6: lane=token dots kernel, proto streamed through SGPRs.
//
// R5 was LDS-pipe bound (broadcast ds_read_b128 ~12cyc feeding 4 fmacs).
// Fix: invert operand flow. lane = token -> x is per-lane (VGPR), proto is
// the broadcast operand -> SGPRs via s_load_dwordx16 from transposed
// ptt[k][e] (256 KB, cache-hot). Hot loop has NO DS ops: per k-step,
// 4 s_load + lgkm drain + 64 v_fmac acc[e], s_p[e], v_x.
//
// K0 repack: proto[e][d] -> ptt[d][e]
// K1 dots:   256 blocks x 512 thr (8 waves). Block = 64 tokens (lane=token),
//            wave w owns d-slice [128w,128w+128). x staged per 16-d chunk
//            into wave-private LDS (coalesced global -> ds_write -> per-lane
//            row reads). Norm sumsq fused into the k-loop. Cross-wave
//            reduction: 4-step LDS tree (buffer unioned with dead x-stage).
//            Output: normalized per-row dots [16384][64] fp32 -> ws.
// K2 window+top2: reads rows s-2,s-1,s from ws (clamped per batch; halo is
//            trivial since all rows are materialized), window-3 sum, top-2
//            butterfly (R5-verified), w1 = 1/(1+exp((l2-l1)/3)).

#define BB 8
#define SS 2048
#define DD 1024
#define EE 64
#define EPSV 1e-8f

#define CHD 16                 // d per staged chunk
#define XSTR 20                // LDS row stride for x chunk (16 + 4 pad)
#define RSTR 68                // LDS row stride for reduction buf (64 + 4 pad)

typedef int v16i __attribute__((ext_vector_type(16)));

#define SL(dst, a, off) \
  asm volatile("s_load_dwordx16 %0, %1, " off : "=s"(dst) : "s"(a))

// 16 fmacs: acc[e0..e0+15] += T[0..15] * xj   (SGPR broadcast x VGPR)
#define FME16(T, e0)                                   \
  acc[(e0) + 0]  += __int_as_float(T[0])  * xj;        \
  acc[(e0) + 1]  += __int_as_float(T[1])  * xj;        \
  acc[(e0) + 2]  += __int_as_float(T[2])  * xj;        \
  acc[(e0) + 3]  += __int_as_float(T[3])  * xj;        \
  acc[(e0) + 4]  += __int_as_float(T[4])  * xj;        \
  acc[(e0) + 5]  += __int_as_float(T[5])  * xj;        \
  acc[(e0) + 6]  += __int_as_float(T[6])  * xj;        \
  acc[(e0) + 7]  += __int_as_float(T[7])  * xj;        \
  acc[(e0) + 8]  += __int_as_float(T[8])  * xj;        \
  acc[(e0) + 9]  += __int_as_float(T[9])  * xj;        \
  acc[(e0) + 10] += __int_as_float(T[10]) * xj;        \
  acc[(e0) + 11] += __int_as_float(T[11]) * xj;        \
  acc[(e0) + 12] += __int_as_float(T[12]) * xj;        \
  acc[(e0) + 13] += __int_as_float(T[13]) * xj;        \
  acc[(e0) + 14] += __int_as_float(T[14]) * xj;        \
  acc[(e0) + 15] += __int_as_float(T[15]) * xj;

// ---- K0: transpose proto[e][d] -> ptt[d][e] --------------------------------
__global__ __launch_bounds__(256) void repack_proto(
    const float* __restrict__ proto, float* __restrict__ ptt) {
  const int gid = blockIdx.x * 256 + threadIdx.x;  // 0..65535
  const int d = gid >> 6;
  const int e = gid & 63;
  ptt[gid] = proto[(size_t)e * DD + d];  // write coalesced, read via L2
}

// ---- K1: per-row normalized dots ------------------------------------------
__global__ __launch_bounds__(512, 2) void router_dots(
    const float* __restrict__ x, const float* __restrict__ ptt,
    float* __restrict__ dots) {
  // union: x-stage regions (8 waves x 64 x XSTR = 10240 f) / reduction bufs
  __shared__ float sb[8 * 64 * XSTR];
  __shared__ float qred[8][64];

  const int lane = threadIdx.x & 63;   // = token within block
  const int w    = __builtin_amdgcn_readfirstlane(threadIdx.x >> 6);
  const int b    = blockIdx.x >> 5;            // 32 blocks per batch
  const int s0   = (blockIdx.x & 31) * 64;

  const float* xb = x + (size_t)b * SS * DD;
  float* xw = sb + w * 64 * XSTR;              // wave-private stage region

  float acc[EE];
#pragma unroll
  for (int e = 0; e < EE; ++e) acc[e] = 0.0f;
  float q = 0.0f;

  // staging assignment (chunk-invariant): 4 float4 per lane
  const int srow = lane >> 2;   // + 16*i
  const int sslt = lane & 3;    // float4 slot within 16-d chunk

  const int dof_w = w * 128;    // this wave's d-slice base

  for (int c = 0; c < 8; ++c) {            // 8 chunks of 16 d
    const int dof = dof_w + c * CHD;
    // ---- stage 64 tokens x 16 d (wave-private; no block barrier) ----
#pragma unroll
    for (int i = 0; i < 4; ++i) {
      const int row = srow + 16 * i;
      const float4 v =
          *(const float4*)(xb + (size_t)(s0 + row) * DD + dof + sslt * 4);
      *(float4*)(&xw[row * XSTR + sslt * 4]) = v;
    }
    // compiler inserts vm/lgkm waits for the ds_read-after-ds_write dep
    // ---- k-loop: 4 k-groups of 4 ----
    for (int kg = 0; kg < 4; ++kg) {
      const float4 xv = *(const float4*)(&xw[lane * XSTR + kg * 4]);
#pragma unroll
      for (int j = 0; j < 4; ++j) {
        const float xj = (j == 0) ? xv.x : (j == 1) ? xv.y : (j == 2) ? xv.z : xv.w;
        const int kglob = dof + kg * 4 + j;
        const unsigned long long pa =
            (unsigned long long)(uintptr_t)(ptt + (size_t)kglob * EE);
        v16i A, B, C, D;
        SL(A, pa, "0x0");
        SL(B, pa, "0x40");
        SL(C, pa, "0x80");
        SL(D, pa, "0xc0");
        // SMEM returns may be out-of-order: full drain only
        asm volatile("s_waitcnt lgkmcnt(0)" : "+s"(A), "+s"(B), "+s"(C), "+s"(D));
        FME16(A, 0)
        FME16(B, 16)
        FME16(C, 32)
        FME16(D, 48)
        q += xj * xj;
      }
    }
  }

  qred[w][lane] = q;

  // ---- cross-wave tree reduction in LDS (acc: 8 partials -> wave 0) ----
  float* R0 = sb;
  float* R1 = sb + 64 * RSTR;   // 4352 floats each; 8704 <= 10240

#define WRACC(R)                                              \
  {                                                           \
    _Pragma("unroll") for (int e4 = 0; e4 < 16; ++e4)         \
        *(float4*)(&(R)[lane * RSTR + e4 * 4]) =              \
            *(const float4*)(&acc[e4 * 4]);                   \
  }
#define ADDACC(R)                                             \
  {                                                           \
    _Pragma("unroll") for (int e4 = 0; e4 < 16; ++e4) {       \
      const float4 t = *(const float4*)(&(R)[lane * RSTR + e4 * 4]); \
      acc[e4 * 4 + 0] += t.x;                                 \
      acc[e4 * 4 + 1] += t.y;                                 \
      acc[e4 * 4 + 2] += t.z;                                 \
      acc[e4 * 4 + 3] += t.w;                                 \
    }                                                         \
  }

  __syncthreads();                       // x-stage regions dead
  if (w == 5) WRACC(R0)
  if (w == 7) WRACC(R1)
  __syncthreads();
  if (w == 4) ADDACC(R0)
  if (w == 6) ADDACC(R1)
  __syncthreads();
  if (w == 4) WRACC(R0)
  if (w == 6) WRACC(R1)
  __syncthreads();
  if (w == 0) ADDACC(R0)
  if (w == 2) ADDACC(R1)
  __syncthreads();
  if (w == 1) WRACC(R0)
  if (w == 3) WRACC(R1)
  __syncthreads();
  if (w == 0) ADDACC(R0)
  if (w == 2) ADDACC(R1)
  __syncthreads();
  if (w == 2) WRACC(R0)
  __syncthreads();
  if (w == 0) {
    ADDACC(R0)
    WRACC(R0)                            // full totals -> R0[tok][e]
  }
  __syncthreads();

  // ---- normalize + coalesced store: wave w -> tokens w*8..w*8+7 ----
#pragma unroll
  for (int i = 0; i < 8; ++i) {
    const int tok = w * 8 + i;
    float qs = 0.0f;
#pragma unroll
    for (int w2 = 0; w2 < 8; ++w2) qs += qred[w2][tok];
    const float inv = 1.0f / fmaxf(sqrtf(qs), EPSV);
    dots[((size_t)b * SS + s0 + tok) * EE + lane] = R0[tok * RSTR + lane] * inv;
  }
}

// ---- K2: window-3 + top-2 + renorm softmax --------------------------------
__global__ __launch_bounds__(256) void router_top2(
    const float* __restrict__ dots, float* __restrict__ out) {
  const int lane = threadIdx.x & 63;   // = expert
  const int gw   = __builtin_amdgcn_readfirstlane(
      blockIdx.x * 4 + (threadIdx.x >> 6));   // 0..1023
  const int t0   = gw * 16;            // 16 tokens per wave
  const int b    = t0 >> 11;
  const int sl0  = t0 & (SS - 1);

  float r[18];
#pragma unroll
  for (int j = 0; j < 18; ++j) {
    int sr = sl0 - 2 + j;
    if (sr < 0) sr = 0;                // causal pad: token 0 replicated
    r[j] = dots[((size_t)b * SS + sr) * EE + lane];
  }

#pragma unroll
  for (int i = 0; i < 16; ++i) {
    float v1 = r[i] + r[i + 1] + r[i + 2];
    int   i1 = lane;
    float v2 = -INFINITY;
    int   i2 = 0;
#pragma unroll
    for (int m = 1; m < 64; m <<= 1) {
      const float ov1 = __shfl_xor(v1, m);
      const int   oi1 = __shfl_xor(i1, m);
      const float ov2 = __shfl_xor(v2, m);
      const int   oi2 = __shfl_xor(i2, m);
      const bool o_beats = (ov1 > v1) || (ov1 == v1 && oi1 < i1);
      if (o_beats) {
        const bool v1_beats_o2 = (v1 > ov2) || (v1 == ov2 && i1 < oi2);
        v2 = v1_beats_o2 ? v1 : ov2;
        i2 = v1_beats_o2 ? i1 : oi2;
        v1 = ov1;
        i1 = oi1;
      } else {
        const bool o1_beats_v2 = (ov1 > v2) || (ov1 == v2 && oi1 < i2);
        if (o1_beats_v2) { v2 = ov1; i2 = oi1; }
      }
    }
    if (lane == 0) {
      const float ex = expf((v2 - v1) * (1.0f / 3.0f));  // <= 1
      const float w1 = 1.0f / (1.0f + ex);
      const size_t o = (size_t)(t0 + i) * 2;
      *(float2*)(out + o) = make_float2((float)i1, (float)i2);
      *(float2*)(out + (size_t)BB * SS * 2 + o) = make_float2(w1, ex * w1);
    }
  }
}

extern "C" void kernel_launch(void* const* d_in, const int* in_sizes, int n_in,
                              void* d_out, int out_size, void* d_ws, size_t ws_size,
                              hipStream_t stream) {
  const float* x     = (const float*)d_in[0];
  const float* proto = (const float*)d_in[1];
  // d_in[2] = attn_mask: unused by the reference output path.
  float* out  = (float*)d_out;
  float* ptt  = (float*)d_ws;                          // 256 KiB transposed proto
  float* dots = (float*)((char*)d_ws + (512 << 10));   // 4 MiB normalized dots

  repack_proto<<<dim3(256), dim3(256), 0, stream>>>(proto, ptt);
  router_dots<<<dim3(BB * (SS / 64)), dim3(512), 0, stream>>>(x, ptt, dots);
  router_top2<<<dim3(256), dim3(256), 0, stream>>>(dots, out);
}

// Round 7
// 136.105 us; speedup vs baseline: 1.8677x; 1.1298x over previous
//
#include <hip/hip_runtime.h>
#include <math.h>

// ClownSelector R7: balanced register-tile dots kernel + array-free top2.
//
// R6 post-mortem: K2 (73us) had r[18] spilled to scratch (VGPR=20!); K1
// (75us) was SMEM-latency-bound (~570cyc exposed per k-step, scalar K$
// thrash). R7:
//  K1: wave = 32 tok x 64 exp, thread tile 4x8 (32 acc). Per k-step:
//      1 ds_read_b128 (x, transposed LDS, conflict-free) + 2 global
//      dwordx4 (proto from ptt[k][e], L2-hot, VMEM pipe) + 32 v_fmac.
//      DS ~15cyc vs VALU 16cyc per wave-k -> VALU-bound. x staged into
//      wave-PRIVATE LDS (in-order DS => no barriers in the K-loop).
//      Block = 4 waves = 4 k-slices (256 each) of the same 32 tokens;
//      deterministic LDS tree reduction ((0+1)+(2+3)) + fused L2-norm
//      (sumsq folded into staging). Grid 512 = 2 blocks/CU.
//  K2: 2 lanes per token (32 experts each), 8 unrolled float4 quads, all
//      scalars (no arrays -> no scratch), one shfl_xor(1) top2 merge.
//      w1 = 1/(1+exp((l2-l1)/3)) (softmax denominator cancels).

#define BB 8
#define SS 2048
#define DD 1024
#define EE 64
#define EPSV 1e-8f

#define FMA4(A, s, P) \
  A.x += (s) * (P).x; A.y += (s) * (P).y; A.z += (s) * (P).z; A.w += (s) * (P).w;

// ---- K0: proto[e][d] -> ptt[d][e] -----------------------------------------
__global__ __launch_bounds__(256) void repack_proto(
    const float* __restrict__ proto, float* __restrict__ ptt) {
  const int gid = blockIdx.x * 256 + threadIdx.x;  // 0..65535
  const int d = gid >> 6;
  const int e = gid & 63;
  ptt[gid] = proto[(size_t)e * DD + d];
}

// ---- K1: normalized per-row dots ------------------------------------------
__global__ __launch_bounds__(256, 2) void router_dots(
    const float* __restrict__ x, const float* __restrict__ ptt,
    float* __restrict__ dots) {
  __shared__ float xt[4][16][36];  // per-wave x chunk, transposed [k][tok]
  __shared__ float B0[32][68];     // reduction buffers (stride mult. of 4)
  __shared__ float B1[32][68];
  __shared__ float nq[4][32];      // per-wave per-token sumsq partials

  const int lane = threadIdx.x & 63;
  const int w    = __builtin_amdgcn_readfirstlane(threadIdx.x >> 6);
  const int b    = blockIdx.x >> 6;          // 64 blocks per batch
  const int s0   = (blockIdx.x & 63) * 32;   // 32 tokens per block

  const int toks = lane & 31;  // staging: token
  const int kh   = lane >> 5;  // staging: k-half (8 floats each)
  const int eg   = lane & 7;   // tile: expert group (8 e)
  const int tg   = lane >> 3;  // tile: token group (4 t)

  const float* xb = x + ((size_t)b * SS + s0) * DD;
  const int kbase = w * 256;   // this wave's k-slice

  float4 acc0[4], acc1[4];
#pragma unroll
  for (int i = 0; i < 4; ++i) {
    acc0[i] = make_float4(0.f, 0.f, 0.f, 0.f);
    acc1[i] = make_float4(0.f, 0.f, 0.f, 0.f);
  }
  float q = 0.0f;

  for (int c = 0; c < 16; ++c) {   // 16 chunks x 16 k = 256 k
    const int dof = kbase + c * 16;
    // ---- stage x transposed (wave-private; DS is in-order per wave) ----
    const float* xs = xb + (size_t)toks * DD + dof + kh * 8;
    const float4 v0 = *(const float4*)(xs);
    const float4 v1 = *(const float4*)(xs + 4);
    q += v0.x * v0.x + v0.y * v0.y + v0.z * v0.z + v0.w * v0.w +
         v1.x * v1.x + v1.y * v1.y + v1.z * v1.z + v1.w * v1.w;
    xt[w][kh * 8 + 0][toks] = v0.x;
    xt[w][kh * 8 + 1][toks] = v0.y;
    xt[w][kh * 8 + 2][toks] = v0.z;
    xt[w][kh * 8 + 3][toks] = v0.w;
    xt[w][kh * 8 + 4][toks] = v1.x;
    xt[w][kh * 8 + 5][toks] = v1.y;
    xt[w][kh * 8 + 6][toks] = v1.z;
    xt[w][kh * 8 + 7][toks] = v1.w;
    // ---- 16 k-steps: b128 x-frag + 2 global proto quads + 32 fmac ----
#pragma unroll
    for (int kk = 0; kk < 16; ++kk) {
      const float4 xf = *(const float4*)(&xt[w][kk][tg * 4]);
      const float* pr = ptt + (size_t)(dof + kk) * EE + eg * 8;
      const float4 p0 = *(const float4*)(pr);
      const float4 p1 = *(const float4*)(pr + 4);
      FMA4(acc0[0], xf.x, p0) FMA4(acc1[0], xf.x, p1)
      FMA4(acc0[1], xf.y, p0) FMA4(acc1[1], xf.y, p1)
      FMA4(acc0[2], xf.z, p0) FMA4(acc1[2], xf.z, p1)
      FMA4(acc0[3], xf.w, p0) FMA4(acc1[3], xf.w, p1)
    }
  }

  // sumsq: combine the two k-halves of each token; lanes 0..31 publish
  q += __shfl_xor(q, 32);
  if (kh == 0) nq[w][toks] = q;

#define WRB(B)                                                  \
  { _Pragma("unroll") for (int i = 0; i < 4; ++i) {             \
      *(float4*)(&(B)[tg * 4 + i][eg * 8])     = acc0[i];       \
      *(float4*)(&(B)[tg * 4 + i][eg * 8 + 4]) = acc1[i]; } }
#define ADDB(B)                                                 \
  { _Pragma("unroll") for (int i = 0; i < 4; ++i) {             \
      const float4 t0 = *(const float4*)(&(B)[tg * 4 + i][eg * 8]);     \
      const float4 t1 = *(const float4*)(&(B)[tg * 4 + i][eg * 8 + 4]); \
      acc0[i].x += t0.x; acc0[i].y += t0.y;                     \
      acc0[i].z += t0.z; acc0[i].w += t0.w;                     \
      acc1[i].x += t1.x; acc1[i].y += t1.y;                     \
      acc1[i].z += t1.z; acc1[i].w += t1.w; } }

  // deterministic tree: ((w0+w1) + (w2+w3))
  __syncthreads();
  if (w == 1) WRB(B0)
  if (w == 3) WRB(B1)
  __syncthreads();
  if (w == 0) ADDB(B0)
  if (w == 2) ADDB(B1)
  __syncthreads();
  if (w == 2) WRB(B0)
  __syncthreads();
  if (w == 0) {
    ADDB(B0)
#pragma unroll
    for (int i = 0; i < 4; ++i) {
      const int row = tg * 4 + i;
      const float qs = nq[0][row] + nq[1][row] + nq[2][row] + nq[3][row];
      const float inv = 1.0f / fmaxf(sqrtf(qs), EPSV);
      float4 o0, o1;
      o0.x = acc0[i].x * inv; o0.y = acc0[i].y * inv;
      o0.z = acc0[i].z * inv; o0.w = acc0[i].w * inv;
      o1.x = acc1[i].x * inv; o1.y = acc1[i].y * inv;
      o1.z = acc1[i].z * inv; o1.w = acc1[i].w * inv;
      float* dp = dots + ((size_t)b * SS + s0 + row) * EE + eg * 8;
      *(float4*)(dp)     = o0;
      *(float4*)(dp + 4) = o1;
    }
  }
}

// ---- K2: window-3 + top-2 + renorm softmax (array-free) --------------------
#define T2UP(s, ei)                                            \
  if ((s) > v1) { v2 = v1; i2 = i1; v1 = (s); i1 = (ei); }     \
  else if ((s) > v2) { v2 = (s); i2 = (ei); }

__global__ __launch_bounds__(256) void router_top2(
    const float* __restrict__ dots, float* __restrict__ out) {
  const int gtid = blockIdx.x * 256 + threadIdx.x;  // 0..32767
  const int tok  = gtid >> 1;          // global token
  const int h    = gtid & 1;           // expert half (32 each)
  const int b    = tok >> 11;
  const int sl   = tok & (SS - 1);
  const int r0   = (sl >= 2) ? sl - 2 : 0;   // causal pad: replicate token 0
  const int r1   = (sl >= 1) ? sl - 1 : 0;

  const float* d0 = dots + ((size_t)b * SS + r0) * EE + h * 32;
  const float* d1 = dots + ((size_t)b * SS + r1) * EE + h * 32;
  const float* d2 = dots + ((size_t)b * SS + sl) * EE + h * 32;

  float v1 = -INFINITY, v2 = -INFINITY;
  int i1 = 0, i2 = 0;
#pragma unroll
  for (int qd = 0; qd < 8; ++qd) {
    const float4 a = *(const float4*)(d0 + qd * 4);
    const float4 c = *(const float4*)(d1 + qd * 4);
    const float4 e = *(const float4*)(d2 + qd * 4);
    const int e0 = h * 32 + qd * 4;
    float s;
    s = a.x + c.x + e.x; T2UP(s, e0 + 0)
    s = a.y + c.y + e.y; T2UP(s, e0 + 1)
    s = a.z + c.z + e.z; T2UP(s, e0 + 2)
    s = a.w + c.w + e.w; T2UP(s, e0 + 3)
  }

  // merge the two halves (partner lane = lane^1); tie -> lower index
  {
    const float ov1 = __shfl_xor(v1, 1);
    const int   oi1 = __shfl_xor(i1, 1);
    const float ov2 = __shfl_xor(v2, 1);
    const int   oi2 = __shfl_xor(i2, 1);
    const bool o_beats = (ov1 > v1) || (ov1 == v1 && oi1 < i1);
    if (o_beats) {
      const bool v1_beats_o2 = (v1 > ov2) || (v1 == ov2 && i1 < oi2);
      v2 = v1_beats_o2 ? v1 : ov2;
      i2 = v1_beats_o2 ? i1 : oi2;
      v1 = ov1;
      i1 = oi1;
    } else {
      const bool o1_beats_v2 = (ov1 > v2) || (ov1 == v2 && oi1 < i2);
      if (o1_beats_v2) { v2 = ov1; i2 = oi1; }
    }
  }

  if (h == 0) {
    const float ex = expf((v2 - v1) * (1.0f / 3.0f));  // <= 1
    const float w1 = 1.0f / (1.0f + ex);
    const size_t o = (size_t)tok * 2;
    *(float2*)(out + o) = make_float2((float)i1, (float)i2);
    *(float2*)(out + (size_t)BB * SS * 2 + o) = make_float2(w1, ex * w1);
  }
}

extern "C" void kernel_launch(void* const* d_in, const int* in_sizes, int n_in,
                              void* d_out, int out_size, void* d_ws, size_t ws_size,
                              hipStream_t stream) {
  const float* x     = (const float*)d_in[0];
  const float* proto = (const float*)d_in[1];
  // d_in[2] = attn_mask: unused by the reference output path.
  float* out  = (float*)d_out;
  float* ptt  = (float*)d_ws;                          // 256 KiB ptt[d][e]
  float* dots = (float*)((char*)d_ws + (512 << 10));   // 4 MiB normalized dots

  repack_proto<<<dim3(256), dim3(256), 0, stream>>>(proto, ptt);
  router_dots<<<dim3(512), dim3(256), 0, stream>>>(x, ptt, dots);
  router_top2<<<dim3(128), dim3(256), 0, stream>>>(dots, out);
}